// Round 4
// baseline (29.960 us; speedup 1.0000x reference)
//
#include <hip/hip_runtime.h>

__device__ __forceinline__ float frcp(float x) { return __builtin_amdgcn_rcpf(x); }

// Woodbury solve for D = 2I + 0.3*(cc^T + ss^T):
//   D^-1 r = 0.5 r - 0.25 * U * M^-1 * (U^T r),  U=[c s],  M = (10/3)I + 0.5 U^T U
__device__ __forceinline__ void solve_row(const float q[5], const float qd[5],
                                          float u0, float u1, float u2, float u3,
                                          float x[5]) {
    float s[5], c[5];
    #pragma unroll
    for (int i = 0; i < 5; ++i) __sincosf(q[i], &s[i], &c[i]);

    float v2 = qd[0]*qd[0] + qd[1]*qd[1] + qd[2]*qd[2] + qd[3]*qd[3] + qd[4]*qd[4];
    float coef = 0.1f * v2 + 9.8f;

    float bu[5] = {0.f, u0, u1, u2, u3};
    float r[5];
    #pragma unroll
    for (int i = 0; i < 5; ++i)
        r[i] = bu[i] - (coef * s[i] + 0.05f * qd[i]);

    float cc = 0.f, cs = 0.f, pc = 0.f, ps = 0.f;
    #pragma unroll
    for (int i = 0; i < 5; ++i) {
        cc += c[i] * c[i];
        cs += c[i] * s[i];
        pc += c[i] * r[i];
        ps += s[i] * r[i];
    }
    float ss = 5.0f - cc;   // ci^2 + si^2 = 1

    const float K = 10.0f / 3.0f;
    float m00 = K + 0.5f * cc;
    float m01 = 0.5f * cs;
    float m11 = K + 0.5f * ss;

    float idet = frcp(m00 * m11 - m01 * m01);
    float y0 = 0.25f * idet * (m11 * pc - m01 * ps);
    float y1 = 0.25f * idet * (m00 * ps - m01 * pc);

    #pragma unroll
    for (int i = 0; i < 5; ++i)
        x[i] = 0.5f * r[i] - (c[i] * y0 + s[i] * y1);
}

// 2 rows/thread: state & out rows pair into 5 aligned float4s, u -> 2 float4s.
__global__ __launch_bounds__(256) void amber_dyn2(
    const float4* __restrict__ st4,   // [Bpairs*5]
    const float4* __restrict__ u4,    // [Bpairs*2]
    float4* __restrict__ out4,        // [Bpairs*5]
    int Bpairs)
{
    int p = blockIdx.x * blockDim.x + threadIdx.x;
    if (p >= Bpairs) return;

    float4 a0 = st4[(size_t)p*5+0], a1 = st4[(size_t)p*5+1], a2 = st4[(size_t)p*5+2],
           a3 = st4[(size_t)p*5+3], a4 = st4[(size_t)p*5+4];
    float4 ua = u4[(size_t)p*2+0], ub = u4[(size_t)p*2+1];

    float q0[5]  = {a0.x, a0.y, a0.z, a0.w, a1.x};
    float qd0[5] = {a1.y, a1.z, a1.w, a2.x, a2.y};
    float q1[5]  = {a2.z, a2.w, a3.x, a3.y, a3.z};
    float qd1[5] = {a3.w, a4.x, a4.y, a4.z, a4.w};

    float x0[5], x1[5];
    solve_row(q0, qd0, ua.x, ua.y, ua.z, ua.w, x0);
    solve_row(q1, qd1, ub.x, ub.y, ub.z, ub.w, x1);

    out4[(size_t)p*5+0] = make_float4(qd0[0], qd0[1], qd0[2], qd0[3]);
    out4[(size_t)p*5+1] = make_float4(qd0[4], x0[0],  x0[1],  x0[2]);
    out4[(size_t)p*5+2] = make_float4(x0[3],  x0[4],  qd1[0], qd1[1]);
    out4[(size_t)p*5+3] = make_float4(qd1[2], qd1[3], qd1[4], x1[0]);
    out4[(size_t)p*5+4] = make_float4(x1[1],  x1[2],  x1[3],  x1[4]);
}

// Scalar tail for odd B (not hit with B=1e6).
__global__ void amber_dyn_tail(const float* __restrict__ state,
                               const float* __restrict__ u,
                               float* __restrict__ out, int row)
{
    float q[5], qd[5];
    #pragma unroll
    for (int i = 0; i < 5; ++i) { q[i] = state[(size_t)row*10 + i]; qd[i] = state[(size_t)row*10 + 5 + i]; }
    float x[5];
    solve_row(q, qd, u[(size_t)row*4+0], u[(size_t)row*4+1], u[(size_t)row*4+2], u[(size_t)row*4+3], x);
    #pragma unroll
    for (int i = 0; i < 5; ++i) { out[(size_t)row*10 + i] = qd[i]; out[(size_t)row*10 + 5 + i] = x[i]; }
}

extern "C" void kernel_launch(void* const* d_in, const int* in_sizes, int n_in,
                              void* d_out, int out_size, void* d_ws, size_t ws_size,
                              hipStream_t stream) {
    // inputs (setup_inputs order): t [1], state [B*10], u [B*4]
    const float* state = (const float*)d_in[1];
    const float* u     = (const float*)d_in[2];
    float* out = (float*)d_out;
    int B = in_sizes[1] / 10;
    int Bpairs = B / 2;

    int block = 256;
    int grid = (Bpairs + block - 1) / block;
    amber_dyn2<<<grid, block, 0, stream>>>(
        (const float4*)state, (const float4*)u, (float4*)out, Bpairs);

    if (B & 1) {
        amber_dyn_tail<<<1, 1, 0, stream>>>(state, u, out, B - 1);
    }
}

// Round 5
// 19.937 us; speedup vs baseline: 1.5027x; 1.5027x over previous
//
#include <hip/hip_runtime.h>

__device__ __forceinline__ float frcp(float x) { return __builtin_amdgcn_rcpf(x); }

#define ROWS 256              // rows per block (= blockDim.x)
#define ROW_F 10              // floats per row
#define BLK_F4 (ROWS * ROW_F / 4)   // 640 float4 per block

__global__ __launch_bounds__(256) void amber_dyn_lds(
    const float4* __restrict__ st4,   // state as float4 stream [B*10/4]
    const float4* __restrict__ u4,    // [B]
    float4* __restrict__ out4,        // [B*10/4]
    int B)
{
    __shared__ float lds[ROWS * ROW_F];        // 10240 B
    float4* lds4 = reinterpret_cast<float4*>(lds);

    const int tid = threadIdx.x;
    const int f4base = blockIdx.x * BLK_F4;
    const int totalF4 = B * ROW_F / 4;         // 2.5e6 fits int

    // ---- stage 1: coalesced global -> LDS (16 B/lane, linear) ----
    #pragma unroll
    for (int it = 0; it < 3; ++it) {
        int i = tid + it * 256;
        if (i < BLK_F4) {
            int g = f4base + i;
            if (g < totalF4) lds4[i] = st4[g];
        }
    }
    __syncthreads();

    // ---- stage 2: per-thread row compute (own row only; no cross-thread) ----
    const int row = blockIdx.x * ROWS + tid;
    if (row < B) {
        float* myrow = lds + tid * ROW_F;
        float q[5], qd[5];
        #pragma unroll
        for (int i = 0; i < 5; ++i) { q[i] = myrow[i]; qd[i] = myrow[5 + i]; }

        float4 uv = u4[row];                   // 16 B/lane, coalesced

        float s[5], c[5];
        #pragma unroll
        for (int i = 0; i < 5; ++i) __sincosf(q[i], &s[i], &c[i]);

        float v2 = qd[0]*qd[0] + qd[1]*qd[1] + qd[2]*qd[2] + qd[3]*qd[3] + qd[4]*qd[4];
        float coef = 0.1f * v2 + 9.8f;

        float bu[5] = {0.f, uv.x, uv.y, uv.z, uv.w};
        float r[5];
        #pragma unroll
        for (int i = 0; i < 5; ++i)
            r[i] = bu[i] - (coef * s[i] + 0.05f * qd[i]);

        // Woodbury: D = 2I + 0.3(cc^T+ss^T);
        // D^-1 r = 0.5 r - 0.25 U M^-1 U^T r, M = (10/3)I + 0.5 U^T U
        float cc = 0.f, cs = 0.f, pc = 0.f, ps = 0.f;
        #pragma unroll
        for (int i = 0; i < 5; ++i) {
            cc += c[i]*c[i]; cs += c[i]*s[i];
            pc += c[i]*r[i]; ps += s[i]*r[i];
        }
        float ss = 5.0f - cc;                  // ci^2+si^2 = 1

        const float K = 10.0f / 3.0f;
        float m00 = K + 0.5f * cc;
        float m01 = 0.5f * cs;
        float m11 = K + 0.5f * ss;

        float idet = frcp(m00 * m11 - m01 * m01);
        float y0 = 0.25f * idet * (m11 * pc - m01 * ps);
        float y1 = 0.25f * idet * (m00 * ps - m01 * pc);

        // in-place: row[0:5] = qd, row[5:10] = x
        #pragma unroll
        for (int i = 0; i < 5; ++i) {
            myrow[i]     = qd[i];
            myrow[5 + i] = 0.5f * r[i] - (c[i] * y0 + s[i] * y1);
        }
    }
    __syncthreads();

    // ---- stage 3: coalesced LDS -> global (16 B/lane, linear) ----
    #pragma unroll
    for (int it = 0; it < 3; ++it) {
        int i = tid + it * 256;
        if (i < BLK_F4) {
            int g = f4base + i;
            if (g < totalF4) out4[g] = lds4[i];
        }
    }
}

extern "C" void kernel_launch(void* const* d_in, const int* in_sizes, int n_in,
                              void* d_out, int out_size, void* d_ws, size_t ws_size,
                              hipStream_t stream) {
    // inputs (setup_inputs order): t [1], state [B*10], u [B*4]
    const float* state = (const float*)d_in[1];
    const float* u     = (const float*)d_in[2];
    float* out = (float*)d_out;
    int B = in_sizes[1] / 10;

    int grid = (B + ROWS - 1) / ROWS;
    amber_dyn_lds<<<grid, ROWS, 0, stream>>>(
        (const float4*)state, (const float4*)u, (float4*)out, B);
}